// Round 14
// baseline (1272.829 us; speedup 1.0000x reference)
//
#include <hip/hip_runtime.h>

#define HN 10

__device__ __forceinline__ float fast_sigmoid(float x) {
    return __builtin_amdgcn_rcpf(1.0f + __expf(-x));
}
__device__ __forceinline__ float fast_tanh(float x) {
    return 2.0f * __builtin_amdgcn_rcpf(1.0f + __expf(-2.0f * x)) - 1.0f;
}

__device__ __forceinline__ float dot10(const float* __restrict__ w, const float* __restrict__ x) {
    float s = 0.0f;
#pragma unroll
    for (int t = 0; t < 10; ++t) s = __builtin_fmaf(w[t], x[t], s);
    return s;
}

// ===== Kernel 0: transpose inputs into stage[90][B] (rows 0..79 = x steps, 80..89 = h0) =====
// Block handles 64 batch rows. Global reads are fully contiguous (block reads 64*80
// sequential floats of neigh, 64*10 of policy); global writes coalesced 256B/wave.
__global__ __launch_bounds__(256, 4) void Piston_PolicyHelper_gru_tin(
    const float* __restrict__ policy,   // [B,10]
    const float* __restrict__ neigh,    // [B,8,10]
    float* __restrict__ stage,          // [90,B]
    int B)
{
    __shared__ float sN[64 * 81];   // 81 % 32 coprime -> conflict-free col reads
    __shared__ float sP[64 * 11];

    const int tid = threadIdx.x;
    const int bbase = blockIdx.x * 64;

    // neigh tile: 64 rows x 80 floats = 1280 float4, contiguous
    const float4* src4 = reinterpret_cast<const float4*>(neigh + (size_t)bbase * 80);
    for (int i = tid; i < 1280; i += 256) {
        float4 v = src4[i];
        int row = i / 20;
        int c = (i - row * 20) * 4;
        float* d = sN + row * 81 + c;
        d[0] = v.x; d[1] = v.y; d[2] = v.z; d[3] = v.w;
    }
    // policy tile: 64 rows x 10 floats = 320 float2, contiguous
    const float2* srcP = reinterpret_cast<const float2*>(policy + (size_t)bbase * 10);
    for (int i = tid; i < 320; i += 256) {
        float2 v = srcP[i];
        int row = i / 5;
        int c = (i - row * 5) * 2;
        sP[row * 11 + c]     = v.x;
        sP[row * 11 + c + 1] = v.y;
    }
    __syncthreads();

    const int lane = tid & 63;   // varies in wave
    const int sub  = tid >> 6;   // wave-uniform 0..3

    // x rows m=0..79: each wave writes 64 contiguous floats per row
    for (int it = 0; it < 20; ++it) {
        int m = it * 4 + sub;
        stage[(size_t)m * B + bbase + lane] = sN[lane * 81 + m];  // LDS stride 81: conflict-free
    }
    // h0 rows m=0..9
    for (int m = sub; m < 10; m += 4) {
        stage[(size_t)(80 + m) * B + bbase + lane] = sP[lane * 11 + m];
    }
}

// ===== Kernel 1: GRU recurrence — ALL global accesses stride-B coalesced =====
__global__ __launch_bounds__(256, 4) void Piston_PolicyHelper_gru_fwd(
    const float* __restrict__ stage,    // [90,B]
    const float* __restrict__ w_ih,     // [30,10]
    const float* __restrict__ w_hh,     // [30,10]
    const float* __restrict__ b_ih,     // [30]
    const float* __restrict__ b_hh,     // [30]
    float* __restrict__ wsH,            // [90,B] h history (row 0..9 = h0)
    int B)
{
    __shared__ __align__(16) float sWI[30 * 12];
    __shared__ __align__(16) float sWH[30 * 12];
    __shared__ float sBI[30];
    __shared__ float sBH[30];

    const int tid = threadIdx.x;
    for (int i = tid; i < 300; i += 256) {
        int r = i / 10;
        int c = i - r * 10;
        sWI[r * 12 + c] = w_ih[i];
        sWH[r * 12 + c] = w_hh[i];
    }
    if (tid < 30) { sBI[tid] = b_ih[tid]; sBH[tid] = b_hh[tid]; }
    __syncthreads();

    const int b = blockIdx.x * 256 + tid;

    float h[10];
#pragma unroll
    for (int j = 0; j < 10; ++j) h[j] = stage[(size_t)(80 + j) * B + b];
#pragma unroll
    for (int j = 0; j < 10; ++j) wsH[(size_t)j * B + b] = h[j];

#pragma unroll
    for (int step = 0; step < 8; ++step) {
        float x[10];
#pragma unroll
        for (int j = 0; j < 10; ++j) x[j] = stage[(size_t)(step * 10 + j) * B + b];
        float hn[10];
#pragma unroll
        for (int j = 0; j < 10; ++j) {
            float ir = sBI[j]      + dot10(sWI + j * 12,        x);
            float iz = sBI[10 + j] + dot10(sWI + (10 + j) * 12, x);
            float in = sBI[20 + j] + dot10(sWI + (20 + j) * 12, x);
            float hr = sBH[j]      + dot10(sWH + j * 12,        h);
            float hz = sBH[10 + j] + dot10(sWH + (10 + j) * 12, h);
            float hg = sBH[20 + j] + dot10(sWH + (20 + j) * 12, h);
            float r = fast_sigmoid(ir + hr);
            float z = fast_sigmoid(iz + hz);
            float n = fast_tanh(in + r * hg);
            hn[j] = (1.0f - z) * n + z * h[j];
        }
        const size_t rowBase = (size_t)((step + 1) * 10) * B + b;
#pragma unroll
        for (int j = 0; j < 10; ++j) {
            h[j] = hn[j];
            wsH[rowBase + (size_t)j * B] = hn[j];
        }
    }
}

// ===== Kernel 2: transpose wsH [90][B] -> out {[B,10] final, [B,9,10] temp} =====
__global__ __launch_bounds__(256, 4) void Piston_PolicyHelper_gru_tr(
    const float* __restrict__ ws,
    float* __restrict__ out,
    int B)
{
    __shared__ float sT[90 * 65];

    const int tid = threadIdx.x;
    const int bbase = blockIdx.x * 64;

    for (int i = tid; i < 1440; i += 256) {
        int row = i >> 4;
        int c4  = i & 15;
        float4 v = *reinterpret_cast<const float4*>(ws + (size_t)row * B + bbase + c4 * 4);
        float* dstRow = sT + row * 65 + c4 * 4;
        dstRow[0] = v.x; dstRow[1] = v.y; dstRow[2] = v.z; dstRow[3] = v.w;
    }
    __syncthreads();

    {
        float2* dst = reinterpret_cast<float2*>(out + (size_t)B * 10 + (size_t)bbase * 90);
        for (int i = tid; i < 2880; i += 256) {
            int e = 2 * i;
            int r = e / 90;
            int c = e - r * 90;
            dst[i] = make_float2(sT[c * 65 + r], sT[(c + 1) * 65 + r]);
        }
    }
    for (int i = tid; i < 640; i += 256) {
        int r = i / 10;
        int c = i - r * 10;
        out[(size_t)(bbase + r) * 10 + c] = sT[(80 + c) * 65 + r];
    }
}

// ===== Fallback (verified R1 kernel) if ws too small =====
__global__ __launch_bounds__(256, 3) void Piston_PolicyHelper_gru_mono(
    const float* __restrict__ policy, const float* __restrict__ neigh,
    const float* __restrict__ w_ih, const float* __restrict__ w_hh,
    const float* __restrict__ b_ih, const float* __restrict__ b_hh,
    float* __restrict__ out, int B)
{
    __shared__ __align__(16) float sWI[30 * 12];
    __shared__ __align__(16) float sWH[30 * 12];
    __shared__ float sBI[30];
    __shared__ float sBH[30];
    __shared__ float sBuf[64 * 91];

    const int tid = threadIdx.x;
    for (int i = tid; i < 300; i += 256) {
        int r = i / 10;
        int c = i - r * 10;
        sWI[r * 12 + c] = w_ih[i];
        sWH[r * 12 + c] = w_hh[i];
    }
    if (tid < 30) { sBI[tid] = b_ih[tid]; sBH[tid] = b_hh[tid]; }
    __syncthreads();

    const int b = blockIdx.x * 256 + tid;
    float hist[90];
    {
        const float2* p = reinterpret_cast<const float2*>(policy + (size_t)b * 10);
#pragma unroll
        for (int i = 0; i < 5; ++i) {
            float2 v = p[i];
            hist[2 * i] = v.x;
            hist[2 * i + 1] = v.y;
        }
    }
    const float4* nb4 = reinterpret_cast<const float4*>(neigh + (size_t)b * 80);
#pragma unroll
    for (int kk = 0; kk < 4; ++kk) {
        float x[20];
#pragma unroll
        for (int i = 0; i < 5; ++i) {
            float4 v = nb4[kk * 5 + i];
            x[4 * i + 0] = v.x; x[4 * i + 1] = v.y; x[4 * i + 2] = v.z; x[4 * i + 3] = v.w;
        }
#pragma unroll
        for (int s = 0; s < 2; ++s) {
            const int step = kk * 2 + s;
            const float* xs = x + s * 10;
            const float* hp = hist + step * 10;
            float*       hq = hist + (step + 1) * 10;
#pragma unroll
            for (int j = 0; j < 10; ++j) {
                float ir = sBI[j]      + dot10(sWI + j * 12,        xs);
                float iz = sBI[10 + j] + dot10(sWI + (10 + j) * 12, xs);
                float in = sBI[20 + j] + dot10(sWI + (20 + j) * 12, xs);
                float hr = sBH[j]      + dot10(sWH + j * 12,        hp);
                float hz = sBH[10 + j] + dot10(sWH + (10 + j) * 12, hp);
                float hg = sBH[20 + j] + dot10(sWH + (20 + j) * 12, hp);
                float r = fast_sigmoid(ir + hr);
                float z = fast_sigmoid(iz + hz);
                float n = fast_tanh(in + r * hg);
                hq[j] = (1.0f - z) * n + z * hp[j];
            }
        }
    }
    {
        float2* d = reinterpret_cast<float2*>(out + (size_t)b * 10);
#pragma unroll
        for (int i = 0; i < 5; ++i)
            d[i] = make_float2(hist[80 + 2 * i], hist[80 + 2 * i + 1]);
    }
    const int chunk = tid >> 6;
    const int lane  = tid & 63;
    float* tempBase = out + (size_t)B * 10;
    for (int c = 0; c < 4; ++c) {
        __syncthreads();
        if (chunk == c) {
#pragma unroll
            for (int j = 0; j < 90; ++j) sBuf[lane * 91 + j] = hist[j];
        }
        __syncthreads();
        float2* dst = reinterpret_cast<float2*>(
            tempBase + ((size_t)blockIdx.x * 256 + c * 64) * 90);
        for (int i = tid; i < 2880; i += 256) {
            int e = 2 * i;
            int row = e / 90;
            int col = e - row * 90;
            int w = row * 91 + col;
            dst[i] = make_float2(sBuf[w], sBuf[w + 1]);
        }
    }
}

extern "C" void kernel_launch(void* const* d_in, const int* in_sizes, int n_in,
                              void* d_out, int out_size, void* d_ws, size_t ws_size,
                              hipStream_t stream) {
    const float* policy = (const float*)d_in[0];
    const float* neigh  = (const float*)d_in[1];
    const float* w_ih   = (const float*)d_in[2];
    const float* w_hh   = (const float*)d_in[3];
    const float* b_ih   = (const float*)d_in[4];
    const float* b_hh   = (const float*)d_in[5];
    float* out = (float*)d_out;

    const int B = in_sizes[0] / HN;   // 262144
    const size_t wsNeed = (size_t)B * 90 * sizeof(float);

    if (ws_size >= wsNeed) {
        float* ws = (float*)d_ws;
        float* stage = out + (size_t)B * 10;   // temp region doubles as x-major staging
        Piston_PolicyHelper_gru_tin<<<B / 64, 256, 0, stream>>>(policy, neigh, stage, B);
        Piston_PolicyHelper_gru_fwd<<<B / 256, 256, 0, stream>>>(
            stage, w_ih, w_hh, b_ih, b_hh, ws, B);
        Piston_PolicyHelper_gru_tr<<<B / 64, 256, 0, stream>>>(ws, out, B);
    } else {
        Piston_PolicyHelper_gru_mono<<<(B + 255) / 256, 256, 0, stream>>>(
            policy, neigh, w_ih, w_hh, b_ih, b_hh, out, B);
    }
}